// Round 9
// baseline (146.026 us; speedup 1.0000x reference)
//
#include <hip/hip_runtime.h>

// KnowledgeConsistentAttention: out = softmax_q( pool3x3(F) . K^T ) . K,  K = normalize(F+eps)
// pool3x3 acts only on the p index of S = F.K^T => flash-style fused kernel with
// Q=G=pool3x3(F), K=V=normalize(F+eps). exp(S) fits fp32 -> no max subtraction.
//
// R9: cooperative 8-wave blocks (512 thr), 128p x 64q tiles. GEMM1 splits q 4-ways
// (wave reads only 8 of 32 K-chunks); GEMM2 splits c 4-ways (8 V-chunks + 8 shared-P
// chunks). Per-CU LDS reads drop ~30% vs R7. P is a block-shared, XOR-granule-swizzled
// fragment image (conflict-free chunk reads). l computed by a ones-row MFMA over P.
// K/V fragment images DMA'd linearly (dbuf); 2 barriers per 64q tile.

#define EPSV 1e-7f

typedef __bf16 bf16x8 __attribute__((ext_vector_type(8)));
typedef float f32x4 __attribute__((ext_vector_type(4)));
typedef unsigned short ushort8v __attribute__((ext_vector_type(8)));

__device__ __forceinline__ unsigned short f2bf(float f) {
    union { float f; unsigned int u; } x; x.f = f;
    unsigned int r = x.u + 0x7FFFu + ((x.u >> 16) & 1u);
    return (unsigned short)(r >> 16);
}

__device__ __forceinline__ f32x4 mfma16(bf16x8 a, bf16x8 b, f32x4 c) {
    return __builtin_amdgcn_mfma_f32_16x16x32_bf16(a, b, c, 0, 0, 0);
}

__device__ __forceinline__ void gload_lds16(const void* g, void* l) {
    __builtin_amdgcn_global_load_lds((const __attribute__((address_space(1))) void*)g,
                                     (__attribute__((address_space(3))) void*)l, 16, 0, 0);
}

// ---------------- prep 1: Kimg (B-frag image) + Vimg (A-frag image), 64q tiles ----------
// Kimg: per (b, 64q-tile T): 32KB = 32 chunks of 1KB; chunk# = kg*4 + ct; lane L holds
//   K[T*64 + ct*16 + (L&15)][kg*32 + (L>>4)*8 + e]          (standard 16x16x32 B layout)
// Vimg: per (b, T): 32KB; chunk# = c16*2 + kq; lane L holds
//   V[T*64 + kq*32 + sigma(L>>4,e)][c16*16 + (L&15)], sigma(g,e)=g*4+(e>>1)+16*(e&1).
__global__ __launch_bounds__(256) void prep_kv(const float* __restrict__ F,
                                               unsigned short* __restrict__ Kimg,
                                               unsigned short* __restrict__ Vimg) {
    __shared__ unsigned short ldsT[256 * 74];   // [c][64q], 148B rows (V gather)
    __shared__ unsigned short ldsR[64 * 264];   // [qloc][c], 528B rows (K frags)
    const int tid = threadIdx.x;
    const int w = tid >> 6, lane = tid & 63;
    const int q0 = blockIdx.x * 64;
    const int b = blockIdx.y;
    const size_t bq = (size_t)b * 4096;

    for (int r = 0; r < 16; ++r) {
        const int qloc = w * 16 + r;
        const int q = q0 + qloc;
        const float4 f = *(const float4*)(F + ((bq + q) << 8) + lane * 4);
        float v0 = f.x + EPSV, v1 = f.y + EPSV, v2 = f.z + EPSV, v3 = f.w + EPSV;
        float ss = v0 * v0 + v1 * v1 + v2 * v2 + v3 * v3;
        #pragma unroll
        for (int m = 1; m <= 32; m <<= 1) ss += __shfl_xor(ss, m);
        const float inv = 1.0f / sqrtf(ss);
        const unsigned short k0 = f2bf(v0 * inv), k1 = f2bf(v1 * inv);
        const unsigned short k2 = f2bf(v2 * inv), k3 = f2bf(v3 * inv);
        ushort4 kk; kk.x = k0; kk.y = k1; kk.z = k2; kk.w = k3;
        *(ushort4*)(ldsR + qloc * 264 + lane * 4) = kk;
        ldsT[(lane * 4 + 0) * 74 + qloc] = k0;
        ldsT[(lane * 4 + 1) * 74 + qloc] = k1;
        ldsT[(lane * 4 + 2) * 74 + qloc] = k2;
        ldsT[(lane * 4 + 3) * 74 + qloc] = k3;
    }
    __syncthreads();

    const size_t tb = (((size_t)b * 64 + blockIdx.x) << 15);  // 32KB/tile

    // ---- K fragments: 2048 granules, 8 per thread ----
    #pragma unroll
    for (int i = 0; i < 8; ++i) {
        const int fi = i * 256 + tid;
        const int chunk = fi >> 6, L = fi & 63;
        const int kg = chunk >> 2, ct = chunk & 3;
        const int qloc = ct * 16 + (L & 15);
        const int c0 = kg * 32 + (L >> 4) * 8;
        *(ushort8v*)((char*)Kimg + tb + fi * 16) = *(const ushort8v*)(ldsR + qloc * 264 + c0);
    }

    // ---- V fragments (sigma slots): thread owns channel c = tid ----
    const int c16v = tid >> 4, l15c = tid & 15;
    const unsigned short* row = ldsT + tid * 74;
    #pragma unroll
    for (int kq = 0; kq < 2; ++kq)
        #pragma unroll
        for (int g4v = 0; g4v < 4; ++g4v) {
            ushort8v frag;
            #pragma unroll
            for (int e = 0; e < 8; ++e)
                frag[e] = row[kq * 32 + g4v * 4 + (e >> 1) + ((e & 1) << 4)];
            *(ushort8v*)((char*)Vimg + tb + (((c16v << 1) + kq) << 10) +
                         ((g4v * 16 + l15c) << 4)) = frag;
        }
}

// ---------------- prep 2: G = pool3x3(F) * 9/cnt (TF SAME), separable, bf16 ----------------
__global__ __launch_bounds__(256) void prep_g(const float* __restrict__ F,
                                              unsigned short* __restrict__ G) {
    __shared__ float vs[64 * 256];
    const int tid = threadIdx.x;
    const int i = blockIdx.x, b = blockIdx.y;
    const size_t bq = (size_t)b * 4096;
    const int i0 = i > 0 ? i - 1 : 0, i1 = i < 63 ? i + 1 : 63;
    #pragma unroll
    for (int k2 = 0; k2 < 16; ++k2) {
        const int cell = k2 * 256 + tid;
        const int j = cell >> 6, c4 = (cell & 63) << 2;
        float4 acc = {0.f, 0.f, 0.f, 0.f};
        for (int ii = i0; ii <= i1; ++ii) {
            const float4 f = *(const float4*)(F + ((bq + ii * 64 + j) << 8) + c4);
            acc.x += f.x; acc.y += f.y; acc.z += f.z; acc.w += f.w;
        }
        *(float4*)(vs + j * 256 + c4) = acc;
    }
    __syncthreads();
    const float ri = (float)(i1 - i0 + 1);
    #pragma unroll
    for (int k2 = 0; k2 < 16; ++k2) {
        const int cell = k2 * 256 + tid;
        const int j = cell >> 6, c4 = (cell & 63) << 2;
        const int j0 = j > 0 ? j - 1 : 0, j1 = j < 63 ? j + 1 : 63;
        float4 s = {0.f, 0.f, 0.f, 0.f};
        for (int jj = j0; jj <= j1; ++jj) {
            const float4 v = *(const float4*)(vs + jj * 256 + c4);
            s.x += v.x; s.y += v.y; s.z += v.z; s.w += v.w;
        }
        const float scale = 9.0f / (ri * (float)(j1 - j0 + 1));
        ushort4 gv; gv.x = f2bf(s.x * scale); gv.y = f2bf(s.y * scale);
        gv.z = f2bf(s.z * scale); gv.w = f2bf(s.w * scale);
        *(ushort4*)(G + ((bq + i * 64 + j) << 8) + c4) = gv;
    }
}

// ---------------- main fused attention ----------------
// grid 512 (XCD-swizzled -> pb[32] x split[4] x b[4]), 512 threads (8 waves).
// Block: 128p, 16 tiles of 64q. GEMM1: wave (ph=w>>2, qg=w&3) computes S[64p x 16q],
// reading 8 K-chunks. exp -> shared P image (XOR-granule swizzle). barrier.
// GEMM2: wave (ph2=w>>2, cg=w&3) computes O^T[64c x 64p] from 8 V + 8 P chunks;
// l via ones-MFMA over P (cg==0). barrier. K/V dbuf staged a full tile ahead.
template <int ATOMIC>
__global__ __launch_bounds__(512, 2) void attn_main(
        const unsigned short* __restrict__ Kimg, const unsigned short* __restrict__ Vimg,
        const unsigned short* __restrict__ G, float* __restrict__ wsl,
        float* __restrict__ dOut, float* __restrict__ wsO) {
    __shared__ unsigned short ldsK[2][16384];  // 2 x 32KB, linear fragment image
    __shared__ unsigned short ldsV[2][16384];  // 2 x 32KB
    __shared__ unsigned short ldsP[8192];      // 16KB: 16 chunks (pc*2+kq), granule-XOR
    const int tid = threadIdx.x;
    const int w = tid >> 6, lane = tid & 63;
    const int l15 = lane & 15, g4 = lane >> 4;
    const int ph = w >> 2, qg = w & 3;   // GEMM1 role
    const int cg = w & 3;                // GEMM2 role (ph2 == ph)

    // XCD-aware decomposition: all 32 pb of a (split,b) group land on one XCD
    const int bid = blockIdx.x;
    const int u = bid & 7, v = bid >> 3;
    const int group = u * 2 + (v >> 5);
    const int pb = v & 31;
    const int split = group >> 2, b = group & 3;

    const size_t bq = (size_t)b * 4096;
    const int pwave = pb * 128 + ph * 64;

    const char* KimgB = (const char*)Kimg + (((size_t)b * 64 + split * 16) << 15);
    const char* VimgB = (const char*)Vimg + (((size_t)b * 64 + split * 16) << 15);

    // prologue: stage tile 0 (linear copies, 4+4 granules per thread)
    #pragma unroll
    for (int it = 0; it < 4; ++it) {
        const int g = it * 512 + tid;
        gload_lds16(KimgB + g * 16, (char*)&ldsK[0][0] + g * 16);
    }
    #pragma unroll
    for (int it = 0; it < 4; ++it) {
        const int g = it * 512 + tid;
        gload_lds16(VimgB + g * 16, (char*)&ldsV[0][0] + g * 16);
    }

    // preload G A-frags: 64 rows x 256 k -> 128 VGPRs
    bf16x8 a[4][8];
    #pragma unroll
    for (int rt = 0; rt < 4; ++rt)
        #pragma unroll
        for (int kg = 0; kg < 8; ++kg)
            a[rt][kg] = *(const bf16x8*)(G + ((bq + pwave + rt * 16 + l15) << 8) + (kg << 5) + (g4 << 3));

    f32x4 o[4][4];   // [i = c16][j = p-colgroup]
    f32x4 ol[4];     // l partial (ones-row), cg==0 only
    #pragma unroll
    for (int i = 0; i < 4; ++i) {
        #pragma unroll
        for (int j = 0; j < 4; ++j) o[i][j] = f32x4{0.f, 0.f, 0.f, 0.f};
        ol[i] = f32x4{0.f, 0.f, 0.f, 0.f};
    }
    bf16x8 ones;
    #pragma unroll
    for (int e = 0; e < 8; ++e) ones[e] = (__bf16)1.0f;

    // P addressing constants
    const int gx = ((l15 >> 2) & 3) << 1;           // write-side granule XOR
    const int ebyte = ((l15 & 3) * 2 + (qg & 1)) * 2;
    const int Lsw = lane ^ ((lane >> 4) << 1);      // read-side swizzled granule

    __syncthreads();  // tile 0 landed

    #pragma unroll 1
    for (int t = 0; t < 16; ++t) {
        const int cur = t & 1;

        // issue stage of tile t+1 (drained at the post-exp barrier, ~a full phase away)
        if (t < 15) {
            const char* ks = KimgB + ((size_t)(t + 1) << 15);
            #pragma unroll
            for (int it = 0; it < 4; ++it) {
                const int g = it * 512 + tid;
                gload_lds16(ks + g * 16, (char*)&ldsK[cur ^ 1][0] + g * 16);
            }
            const char* vsrc = VimgB + ((size_t)(t + 1) << 15);
            #pragma unroll
            for (int it = 0; it < 4; ++it) {
                const int g = it * 512 + tid;
                gload_lds16(vsrc + g * 16, (char*)&ldsV[cur ^ 1][0] + g * 16);
            }
        }

        // ---- GEMM1: S[64p x 16q(qg)] ; 8 contiguous K-chunk reads ----
        f32x4 s[4];
        #pragma unroll
        for (int rt = 0; rt < 4; ++rt) s[rt] = f32x4{0.f, 0.f, 0.f, 0.f};
        const char* kb = (const char*)&ldsK[cur][0] + (qg << 10) + (lane << 4);
        __builtin_amdgcn_s_setprio(1);
        #pragma unroll
        for (int kg = 0; kg < 8; ++kg) {
            const bf16x8 bk = *(const bf16x8*)(kb + (kg << 12));
            #pragma unroll
            for (int rt = 0; rt < 4; ++rt) s[rt] = mfma16(a[rt][kg], bk, s[rt]);
        }
        __builtin_amdgcn_s_setprio(0);

        // ---- exp + P writes (B-frag image, granule-XOR) ----
        #pragma unroll
        for (int rt = 0; rt < 4; ++rt) {
            char* pw = (char*)ldsP + ((((ph * 4 + rt) << 1) + (qg >> 1)) << 10);
            #pragma unroll
            for (int r = 0; r < 4; ++r) {
                const float e = __expf(s[rt][r]);
                const int gsw = ((l15 >> 2) * 16 + g4 * 4 + r) ^ gx;
                union { __bf16 h; unsigned short us; } cv; cv.h = (__bf16)e;
                *(unsigned short*)(pw + gsw * 16 + ebyte) = cv.us;
            }
        }

        __syncthreads();  // P complete; staged t+1 drained

        // ---- GEMM2: O^T[64c(cg) x 64p(ph)] += V @ P ----
        __builtin_amdgcn_s_setprio(1);
        #pragma unroll
        for (int kq = 0; kq < 2; ++kq) {
            bf16x8 pa[4];
            #pragma unroll
            for (int j = 0; j < 4; ++j)
                pa[j] = *(const bf16x8*)((const char*)ldsP +
                            ((((ph * 4 + j) << 1) + kq) << 10) + Lsw * 16);
            #pragma unroll
            for (int i = 0; i < 4; ++i) {
                const bf16x8 bv = *(const bf16x8*)((const char*)&ldsV[cur][0] +
                                    ((((cg * 4 + i) << 1) + kq) << 10) + (lane << 4));
                #pragma unroll
                for (int j = 0; j < 4; ++j) o[i][j] = mfma16(bv, pa[j], o[i][j]);
            }
            if (cg == 0) {
                #pragma unroll
                for (int j = 0; j < 4; ++j) ol[j] = mfma16(ones, pa[j], ol[j]);
            }
        }
        __builtin_amdgcn_s_setprio(0);

        __syncthreads();  // P consumed; buffer handoff
    }

    // ---- epilogue ----
    // l: ones-row output, every row equal; take g4==0, reg 0
    if (cg == 0 && g4 == 0) {
        #pragma unroll
        for (int j = 0; j < 4; ++j)
            wsl[(size_t)split * 16384 + bq + pb * 128 + ph * 64 + j * 16 + l15] = ol[j][0];
    }
    // O^T: p = pb*128 + ph*64 + j*16 + l15 ; c = cg*64 + i*16 + g4*4 + r
    if (!ATOMIC) {
        float* dst = (split == 0) ? dOut : (wsO + (size_t)(split - 1) * 4194304);
        #pragma unroll
        for (int i = 0; i < 4; ++i)
            #pragma unroll
            for (int j = 0; j < 4; ++j)
                *(f32x4*)(dst + ((bq + pb * 128 + ph * 64 + j * 16 + l15) << 8) +
                          cg * 64 + i * 16 + (g4 << 2)) = o[i][j];
    } else {
        #pragma unroll
        for (int i = 0; i < 4; ++i)
            #pragma unroll
            for (int j = 0; j < 4; ++j)
                #pragma unroll
                for (int r = 0; r < 4; ++r) {
                    const size_t idx = ((bq + pb * 128 + ph * 64 + j * 16 + l15) << 8) +
                                       cg * 64 + i * 16 + (g4 << 2) + r;
                    atomicAdd(&dOut[idx], o[i][j][r]);
                }
    }
}

// ---------------- finalize: sum q-split partials, divide by l ----------------
__global__ __launch_bounds__(256) void reduce_fin(float* __restrict__ dOut,
                                                  const float* __restrict__ wsO,
                                                  const float* __restrict__ wsl) {
    const int i4 = blockIdx.x * 256 + threadIdx.x;
    const int row = i4 >> 6;
    const float l = wsl[row] + wsl[16384 + row] + wsl[32768 + row] + wsl[49152 + row];
    const float inv = 1.0f / l;
    float4 v = ((const float4*)dOut)[i4];
    const float4 a = ((const float4*)wsO)[i4];
    const float4 b = ((const float4*)(wsO + 4194304))[i4];
    const float4 c = ((const float4*)(wsO + 8388608))[i4];
    v.x = (v.x + a.x + b.x + c.x) * inv;
    v.y = (v.y + a.y + b.y + c.y) * inv;
    v.z = (v.z + a.z + b.z + c.z) * inv;
    v.w = (v.w + a.w + b.w + c.w) * inv;
    ((float4*)dOut)[i4] = v;
}

__global__ __launch_bounds__(256) void divide_fin(float* __restrict__ dOut,
                                                  const float* __restrict__ wsl) {
    const int i4 = blockIdx.x * 256 + threadIdx.x;
    const int row = i4 >> 6;
    const float l = wsl[row] + wsl[16384 + row] + wsl[32768 + row] + wsl[49152 + row];
    const float inv = 1.0f / l;
    float4 v = ((const float4*)dOut)[i4];
    v.x *= inv; v.y *= inv; v.z *= inv; v.w *= inv;
    ((float4*)dOut)[i4] = v;
}

extern "C" void kernel_launch(void* const* d_in, const int* in_sizes, int n_in,
                              void* d_out, int out_size, void* d_ws, size_t ws_size,
                              hipStream_t stream) {
    const float* F = (const float*)d_in[0];
    // d_in[1] (masks) has no effect on the output.
    float* out = (float*)d_out;
    char* ws = (char*)d_ws;

    // ws layout: Kimg bf16 frag image (8MB) @0 | Vimg bf16 frag image (8MB) @8MB |
    //            G bf16 [4][4096][256] @16MB | wsl f32 [4][16384] @24MB (256KB) |
    //            wsO f32 3x[4][4096][256] @24.25MB (48MB)
    unsigned short* Kimg = (unsigned short*)ws;
    unsigned short* Vimg = Kimg + 4194304;
    unsigned short* G = Vimg + 4194304;
    float* wsl = (float*)(ws + 25165824);
    float* wsO = (float*)(ws + 25165824 + 262144);
    const size_t needA = 25165824u + 262144u + 3u * 16777216u;

    prep_kv<<<dim3(64, 4), 256, 0, stream>>>(F, Kimg, Vimg);
    prep_g<<<dim3(64, 4), 256, 0, stream>>>(F, G);

    if (ws_size >= needA) {
        attn_main<0><<<dim3(512), 512, 0, stream>>>(Kimg, Vimg, G, wsl, out, wsO);
        reduce_fin<<<4096, 256, 0, stream>>>(out, wsO, wsl);
    } else {
        hipMemsetAsync(out, 0, 16777216, stream);
        attn_main<1><<<dim3(512), 512, 0, stream>>>(Kimg, Vimg, G, wsl, out, nullptr);
        divide_fin<<<4096, 256, 0, stream>>>(out, wsl);
    }
}